// Round 6
// baseline (479.317 us; speedup 1.0000x reference)
//
#include <hip/hip_runtime.h>
#include <math.h>

#define NQ 6
#define NL 3

typedef float v2f __attribute__((ext_vector_type(2)));

// ---------- compile-time CNOT-ring permutation ----------
constexpr int cnot_map(int k, int ctrl, int tgt) {
    const int cb = 1 << (5 - ctrl), tb = 1 << (5 - tgt);
    return (k & cb) ? (k ^ tb) : k;
}
constexpr int ring_map(int k) {
    k = cnot_map(k, 5, 0);
    k = cnot_map(k, 4, 5);
    k = cnot_map(k, 3, 4);
    k = cnot_map(k, 2, 3);
    k = cnot_map(k, 1, 2);
    k = cnot_map(k, 0, 1);
    return k;
}

// Lane-split layout: lane parity h holds logical indices k = (h<<5)|s, s in [0,32).
struct RingTab {
    int srcslot[2][32];
    int recvidx[2][32];
    int stage_src[2][32];
    int m;
};
constexpr RingTab make_ring() {
    RingTab T{};
    int cnt[2] = {0, 0};
    int crossdst[2][32] = {};
    int crosssrc[2][32] = {};
    for (int h = 0; h < 2; h++)
        for (int s = 0; s < 32; s++) {
            const int k = (h << 5) | s;
            const int j = ring_map(k);
            T.srcslot[h][s] = j & 31;
            T.recvidx[h][s] = -1;
            if ((j >> 5) != h) {
                crossdst[h][cnt[h]] = s;
                crosssrc[h][cnt[h]] = j & 31;
                cnt[h]++;
            }
        }
    T.m = cnt[0];
    for (int i = 0; i < T.m; i++) {
        T.recvidx[0][crossdst[0][i]] = i;
        T.recvidx[1][crossdst[1][i]] = i;
        T.stage_src[0][i] = crosssrc[1][i];
        T.stage_src[1][i] = crosssrc[0][i];
    }
    return T;
}
constexpr RingTab RT = make_ring();
static_assert(RT.m == 16, "expected 16 cross-lane exchanges per ring");

// xor-1 lane swap: DPP quad_perm [1,0,3,2] — 1 VALU instr, no LDS pipe
__device__ __forceinline__ float dpp1(float v) {
    return __builtin_bit_cast(float,
        __builtin_amdgcn_update_dpp(0, __builtin_bit_cast(int, v),
                                    0xB1, 0xF, 0xF, true));
}
__device__ __forceinline__ v2f dpp1v(v2f v) {
    v2f r; r.x = dpp1(v.x); r.y = dpp1(v.y); return r;
}

// ---- prep kernel: M = RZ(a2)@RY(a1)@RZ(a0), SU(2) form (m00, m01) ----
__global__ void gate_prep(const float* __restrict__ w, float4* __restrict__ M) {
    const int g = threadIdx.x;
    if (g >= NL * NQ) return;
    const float a0 = w[g * 3 + 0], a1 = w[g * 3 + 1], a2 = w[g * 3 + 2];
    const float ch = cosf(0.5f * a1), sh = sinf(0.5f * a1);
    const float cp = cosf(0.5f * (a0 + a2)), sp = sinf(0.5f * (a0 + a2));
    const float cm = cosf(0.5f * (a0 - a2)), sm = sinf(0.5f * (a0 - a2));
    M[g] = make_float4(ch * cp, -ch * sp, -sh * cm, -sh * sm);
}

__global__ __launch_bounds__(256)
void qsim_kernel(const float* __restrict__ x, const float4* __restrict__ M,
                 float* __restrict__ out, int B) {
    const int tid = blockIdx.x * blockDim.x + threadIdx.x;
    const int b = tid >> 1;
    if (b >= B) return;
    const bool h0 = (tid & 1) == 0;

    const float2* x2 = (const float2*)x;
    const float2 v0 = x2[b * 3 + 0];
    const float2 v1 = x2[b * 3 + 1];
    const float2 v2 = x2[b * 3 + 2];
    const float xi[NQ] = {v0.x, v0.y, v1.x, v1.y, v2.x, v2.y};

    // phi = (pi/2)*tanh(x); sin/cos via raw v_sin/v_cos (revolutions, |arg|<=0.25
    // so no range reduction needed): sin(pi/2*t) = sin(2*pi*(t/4))
    float C[NQ], S[NQ];
#pragma unroll
    for (int i = 0; i < NQ; i++) {
        // e^{2x} = 2^{x * 2*log2(e)}; v_exp_f32 computes 2^x
        const float e = __builtin_amdgcn_exp2f(2.885390081777927f * xi[i]);
        const float t = 1.0f - 2.0f * __builtin_amdgcn_rcpf(e + 1.0f);     // tanh(x)
        S[i] = __builtin_amdgcn_sinf(0.25f * t);
        C[i] = __builtin_amdgcn_cosf(0.25f * t);
    }

    // packed state: slot s = 2v+c  ->  R[v] component c (real), I[v] (imag)
    v2f R[16], I[16];
#pragma unroll
    for (int v = 0; v < 16; v++) { R[v] = (v2f)(0.0f); I[v] = (v2f)(0.0f); }

    // ---- layer 0 acting on |0>: product-state cascade ----
    {
        const float4 m0 = M[0];
        const float c = C[0], s = S[0];
        const float g00r = m0.x * c + m0.z * s, g00i = m0.y * c + m0.w * s;
        const float g01r = m0.z * c - m0.x * s, g01i = m0.w * c - m0.y * s;
        R[0].x = h0 ? g00r : -g01r;
        I[0].x = h0 ? g00i : g01i;
    }
#pragma unroll
    for (int q = 1; q < NQ; q++) {
        const float4 mq = M[q];
        const float c = C[q], s = S[q];
        const float g00r = mq.x * c + mq.z * s, g00i = mq.y * c + mq.w * s;
        const float g01r = mq.z * c - mq.x * s, g01i = mq.w * c - mq.y * s;
        const float Ar = g00r, Ai = g00i;     // bit=0 factor (g00)
        const float Br = -g01r, Bi = g01i;    // bit=1 factor (-conj(g01))
        if (q < 5) {
            const int bbit = 1 << (5 - q);
            const int prevmask = (0x1F << (6 - q)) & 0x1F;
#pragma unroll
            for (int v = 0; v < 16; v++) {
                const int s2 = 2 * v;
                if ((s2 & (~prevmask & 31)) == 0) {
                    const int vd = v | (bbit >> 1);
                    const v2f pr = R[v], pi = I[v];
                    R[vd] = pr * Br - pi * Bi;
                    I[vd] = pr * Bi + pi * Br;
                    R[v]  = pr * Ar - pi * Ai;
                    I[v]  = pr * Ai + pi * Ar;
                }
            }
        } else {
            // q=5: intra-vector fill (odd slot from even slot)
            v2f KA; KA.x = Ar; KA.y = Br;
            v2f KB; KB.x = Ai; KB.y = Bi;
#pragma unroll
            for (int v = 0; v < 16; v++) {
                const float pr = R[v].x, pi = I[v].x;
                R[v] = pr * KA - pi * KB;
                I[v] = pr * KB + pi * KA;
            }
        }
    }

    // ---- ring restoration (physical re-canonicalization after CNOT ring) ----
    auto RD = [&](int s) -> float { return (s & 1) ? R[s >> 1].y : R[s >> 1].x; };
    auto ID = [&](int s) -> float { return (s & 1) ? I[s >> 1].y : I[s >> 1].x; };

    auto do_ring = [&]() {
        float er[16], ei[16];
#pragma unroll
        for (int i = 0; i < 16; i++) {
            const int a0 = RT.stage_src[0][i], a1 = RT.stage_src[1][i];
            const float pr = (a0 == a1) ? RD(a0) : (h0 ? RD(a0) : RD(a1));
            const float pm = (a0 == a1) ? ID(a0) : (h0 ? ID(a0) : ID(a1));
            er[i] = dpp1(pr);
            ei[i] = dpp1(pm);
        }
        float nr[32], ni[32];
#pragma unroll
        for (int s = 0; s < 32; s++) {
            const int i0 = RT.recvidx[0][s], i1 = RT.recvidx[1][s];
            const float v0r = (i0 >= 0) ? er[i0] : RD(RT.srcslot[0][s]);
            const float v0i = (i0 >= 0) ? ei[i0] : ID(RT.srcslot[0][s]);
            const float v1r = (i1 >= 0) ? er[i1] : RD(RT.srcslot[1][s]);
            const float v1i = (i1 >= 0) ? ei[i1] : ID(RT.srcslot[1][s]);
            nr[s] = h0 ? v0r : v1r;
            ni[s] = h0 ? v0i : v1i;
        }
#pragma unroll
        for (int v = 0; v < 16; v++) {
            R[v].x = nr[2 * v]; R[v].y = nr[2 * v + 1];
            I[v].x = ni[2 * v]; I[v].y = ni[2 * v + 1];
        }
    };

    auto dense_layer = [&](int layer) {
        // ---- q = 0: cross-lane gate via DPP ----
        {
            const float4 mq = M[layer * NQ + 0];
            const float c = C[0], s = S[0];
            const float g00r = mq.x * c + mq.z * s, g00i = mq.y * c + mq.w * s;
            const float g01r = mq.z * c - mq.x * s, g01i = mq.w * c - mq.y * s;
            const float alr = g00r;
            const float ali = h0 ? g00i : -g00i;
            const float gmr = h0 ? g01r : -g01r;
            const float gmi = g01i;
#pragma unroll
            for (int v = 0; v < 16; v++) {
                const v2f R0 = R[v], I0 = I[v];
                const v2f Rp = dpp1v(R0), Ip = dpp1v(I0);
                R[v] = R0 * alr - I0 * ali + Rp * gmr - Ip * gmi;
                I[v] = I0 * alr + R0 * ali + Ip * gmr + Rp * gmi;
            }
        }
        // ---- q = 1..4: vector-aligned gates (pure pk ops) ----
#pragma unroll
        for (int q = 1; q < 5; q++) {
            const float4 mq = M[layer * NQ + q];
            const float c = C[q], s = S[q];
            const float g00r = mq.x * c + mq.z * s, g00i = mq.y * c + mq.w * s;
            const float g01r = mq.z * c - mq.x * s, g01i = mq.w * c - mq.y * s;
            const int bv = (1 << (5 - q)) >> 1;   // vector-index stride
#pragma unroll
            for (int v = 0; v < 16; v++) {
                if (!(v & bv)) {
                    const int v2_ = v | bv;
                    const v2f R0 = R[v], I0 = I[v];
                    const v2f R1 = R[v2_], I1 = I[v2_];
                    R[v]   = R0 * g00r - I0 * g00i + R1 * g01r - I1 * g01i;
                    I[v]   = I0 * g00r + R0 * g00i + I1 * g01r + R1 * g01i;
                    R[v2_] = R1 * g00r + I1 * g00i - R0 * g01r - I0 * g01i;
                    I[v2_] = I1 * g00r - R1 * g00i - I0 * g01r + R0 * g01i;
                }
            }
        }
        // ---- q = 5: intra-vector gate via .xx/.yy broadcasts ----
        {
            const float4 mq = M[layer * NQ + 5];
            const float c = C[5], s = S[5];
            const float g00r = mq.x * c + mq.z * s, g00i = mq.y * c + mq.w * s;
            const float g01r = mq.z * c - mq.x * s, g01i = mq.w * c - mq.y * s;
            v2f P1; P1.x =  g00r; P1.y = -g01r;
            v2f P2; P2.x = -g00i; P2.y = -g01i;
            v2f P3; P3.x =  g01r; P3.y =  g00r;
            v2f P4; P4.x = -g01i; P4.y =  g00i;
#pragma unroll
            for (int v = 0; v < 16; v++) {
                const v2f Rv = R[v], Iv = I[v];
                const v2f Rxx = Rv.xx, Ryy = Rv.yy, Ixx = Iv.xx, Iyy = Iv.yy;
                R[v] = Rxx * P1 + Ixx * P2 + Ryy * P3 + Iyy * P4;
                I[v] = Ixx * P1 - Rxx * P2 + Iyy * P3 - Ryy * P4;
            }
        }
    };

    do_ring();
    dense_layer(1);
    do_ring();
    dense_layer(2);
    do_ring();

    // ---- expvals: packed partial sums + DPP pair-reduce ----
    v2f Pp = (v2f)(0.0f);
    v2f Tp[5];
#pragma unroll
    for (int q = 0; q < 5; q++) Tp[q] = (v2f)(0.0f);
#pragma unroll
    for (int v = 0; v < 16; v++) {
        const v2f P2 = R[v] * R[v] + I[v] * I[v];
        Pp += P2;
        const int s2 = 2 * v;
        if (s2 & 16) Tp[0] += P2;
        if (s2 & 8)  Tp[1] += P2;
        if (s2 & 4)  Tp[2] += P2;
        if (s2 & 2)  Tp[3] += P2;
        Tp[4] += P2;   // only .y (odd slots) used
    }
    const float P = Pp.x + Pp.y;
    float T[5];
#pragma unroll
    for (int q = 0; q < 4; q++) T[q] = Tp[q].x + Tp[q].y;
    T[4] = Tp[4].y;

    float acc[NQ];
    {
        const float d = h0 ? P : -P;
        acc[0] = d + dpp1(d);
    }
    const float Ptot = P + dpp1(P);
#pragma unroll
    for (int q = 1; q < NQ; q++) {
        const float Tt = T[q - 1] + dpp1(T[q - 1]);
        acc[q] = Ptot - 2.0f * Tt;
    }
    const int off = b * 6 + (h0 ? 0 : 3);
    out[off + 0] = acc[h0 ? 0 : 3];
    out[off + 1] = acc[h0 ? 1 : 4];
    out[off + 2] = acc[h0 ? 2 : 5];
}

extern "C" void kernel_launch(void* const* d_in, const int* in_sizes, int n_in,
                              void* d_out, int out_size, void* d_ws, size_t ws_size,
                              hipStream_t stream) {
    const float* x = (const float*)d_in[0];
    const float* w = (const float*)d_in[1];
    float* out = (float*)d_out;
    float4* M = (float4*)d_ws;  // 18 * 16 B
    const int B = in_sizes[0] / NQ;
    gate_prep<<<1, 64, 0, stream>>>(w, M);
    const int threads = 2 * B;
    const int block = 256;
    const int grid = (threads + block - 1) / block;
    qsim_kernel<<<grid, block, 0, stream>>>(x, M, out, B);
}

// Round 7
// 140.629 us; speedup vs baseline: 3.4084x; 3.4084x over previous
//
#include <hip/hip_runtime.h>
#include <math.h>

#define NQ 6
#define NL 3

// ---------- compile-time CNOT-ring permutation ----------
constexpr int cnot_map(int k, int ctrl, int tgt) {
    const int cb = 1 << (5 - ctrl), tb = 1 << (5 - tgt);
    return (k & cb) ? (k ^ tb) : k;
}
// gather map: s'[k] = s[ring_map(k)]  (validated rounds 2-6)
constexpr int ring_map(int k) {
    k = cnot_map(k, 5, 0);
    k = cnot_map(k, 4, 5);
    k = cnot_map(k, 3, 4);
    k = cnot_map(k, 2, 3);
    k = cnot_map(k, 1, 2);
    k = cnot_map(k, 0, 1);
    return k;
}

// Lane-split layout: lane parity h holds logical indices k = (h<<5)|s, s in [0,32).
struct RingTab {
    int srcslot[2][32];
    int recvidx[2][32];
    int stage_src[2][32];
    int m;
};
constexpr RingTab make_ring() {
    RingTab T{};
    int cnt[2] = {0, 0};
    int crossdst[2][32] = {};
    int crosssrc[2][32] = {};
    for (int h = 0; h < 2; h++)
        for (int s = 0; s < 32; s++) {
            const int k = (h << 5) | s;
            const int j = ring_map(k);
            T.srcslot[h][s] = j & 31;
            T.recvidx[h][s] = -1;
            if ((j >> 5) != h) {
                crossdst[h][cnt[h]] = s;
                crosssrc[h][cnt[h]] = j & 31;
                cnt[h]++;
            }
        }
    T.m = cnt[0];
    for (int i = 0; i < T.m; i++) {
        T.recvidx[0][crossdst[0][i]] = i;
        T.recvidx[1][crossdst[1][i]] = i;
        T.stage_src[0][i] = crosssrc[1][i];
        T.stage_src[1][i] = crosssrc[0][i];
    }
    return T;
}
constexpr RingTab RT = make_ring();
static_assert(RT.m == 16, "expected 16 cross-lane exchanges per ring");

// xor-1 lane swap: DPP quad_perm [1,0,3,2] — 1 VALU instr, no LDS pipe, no waits
__device__ __forceinline__ float dpp1(float v) {
    return __builtin_bit_cast(float,
        __builtin_amdgcn_update_dpp(0, __builtin_bit_cast(int, v),
                                    0xB1, 0xF, 0xF, true));
}

// ---- prep kernel: M = RZ(a2)@RY(a1)@RZ(a0), SU(2) form (m00, m01) ----
__global__ void gate_prep(const float* __restrict__ w, float4* __restrict__ M) {
    const int g = threadIdx.x;
    if (g >= NL * NQ) return;
    const float a0 = w[g * 3 + 0], a1 = w[g * 3 + 1], a2 = w[g * 3 + 2];
    const float ch = cosf(0.5f * a1), sh = sinf(0.5f * a1);
    const float cp = cosf(0.5f * (a0 + a2)), sp = sinf(0.5f * (a0 + a2));
    const float cm = cosf(0.5f * (a0 - a2)), sm = sinf(0.5f * (a0 - a2));
    M[g] = make_float4(ch * cp, -ch * sp, -sh * cm, -sh * sm);
}

__global__ __launch_bounds__(256)
void qsim_kernel(const float* __restrict__ x, const float4* __restrict__ M,
                 float* __restrict__ out, int B) {
    const int tid = blockIdx.x * blockDim.x + threadIdx.x;
    const int b = tid >> 1;
    if (b >= B) return;
    const bool h0 = (tid & 1) == 0;

    const float2* x2 = (const float2*)x;
    const float2 v0 = x2[b * 3 + 0];
    const float2 v1 = x2[b * 3 + 1];
    const float2 v2 = x2[b * 3 + 2];
    const float xi[NQ] = {v0.x, v0.y, v1.x, v1.y, v2.x, v2.y};

    // phi = (pi/2)*tanh(x); v_sin/v_cos take REVOLUTIONS: sin(pi/2*t)=sin(2pi*(t/4)),
    // |t/4|<=0.25 so no range reduction needed.
    float C[NQ], S[NQ];
#pragma unroll
    for (int i = 0; i < NQ; i++) {
        const float e = __builtin_amdgcn_exp2f(2.885390081777927f * xi[i]); // e^{2x}
        const float t = 1.0f - 2.0f * __builtin_amdgcn_rcpf(e + 1.0f);      // tanh(x)
        S[i] = __builtin_amdgcn_sinf(0.25f * t);
        C[i] = __builtin_amdgcn_cosf(0.25f * t);
    }

    float ar[32], ai[32];  // amplitudes for logical k = (h<<5)|s

    // ---- layer 0 acting on |0>: product-state cascade ----
    {
        const float4 m0 = M[0];
        const float c = C[0], s = S[0];
        const float g00r = m0.x * c + m0.z * s, g00i = m0.y * c + m0.w * s;
        const float g01r = m0.z * c - m0.x * s, g01i = m0.w * c - m0.y * s;
        ar[0] = h0 ? g00r : -g01r;
        ai[0] = h0 ? g00i : g01i;
    }
#pragma unroll
    for (int q = 1; q < NQ; q++) {
        const float4 mq = M[q];
        const float c = C[q], s = S[q];
        const float g00r = mq.x * c + mq.z * s, g00i = mq.y * c + mq.w * s;
        const float g01r = mq.z * c - mq.x * s, g01i = mq.w * c - mq.y * s;
        const float Ar = g00r, Ai = g00i;     // bit=0 factor
        const float Br = -g01r, Bi = g01i;    // bit=1 factor (-conj(g01))
        const int bbit = 1 << (5 - q);
        const int prevmask = (0x1F << (6 - q)) & 0x1F;
#pragma unroll
        for (int s2 = 0; s2 < 32; s2++) {
            if ((s2 & (~prevmask & 31)) == 0) {
                const float pr = ar[s2], pi = ai[s2];
                ar[s2 | bbit] = pr * Br - pi * Bi;
                ai[s2 | bbit] = pr * Bi + pi * Br;
                ar[s2] = pr * Ar - pi * Ai;
                ai[s2] = pr * Ai + pi * Ar;
            }
        }
    }

    // ---- ring restoration (re-canonicalize after CNOT ring) ----
    auto do_ring = [&]() {
        float rr[16], ri[16];
#pragma unroll
        for (int i = 0; i < RT.m; i++) {
            const float str = h0 ? ar[RT.stage_src[0][i]] : ar[RT.stage_src[1][i]];
            const float sti = h0 ? ai[RT.stage_src[0][i]] : ai[RT.stage_src[1][i]];
            rr[i] = dpp1(str);
            ri[i] = dpp1(sti);
        }
        float nr[32], ni[32];
#pragma unroll
        for (int s2 = 0; s2 < 32; s2++) {
            const int i0 = RT.recvidx[0][s2], i1 = RT.recvidx[1][s2];
            const float v0r = (i0 >= 0) ? rr[i0] : ar[RT.srcslot[0][s2]];
            const float v0i = (i0 >= 0) ? ri[i0] : ai[RT.srcslot[0][s2]];
            const float v1r = (i1 >= 0) ? rr[i1] : ar[RT.srcslot[1][s2]];
            const float v1i = (i1 >= 0) ? ri[i1] : ai[RT.srcslot[1][s2]];
            nr[s2] = h0 ? v0r : v1r;
            ni[s2] = h0 ? v0i : v1i;
        }
#pragma unroll
        for (int s2 = 0; s2 < 32; s2++) { ar[s2] = nr[s2]; ai[s2] = ni[s2]; }
    };

    auto dense_layer = [&](int layer) {
        // ---- q = 0: cross-lane gate via DPP ----
        {
            const float4 mq = M[layer * NQ + 0];
            const float c = C[0], s = S[0];
            const float g00r = mq.x * c + mq.z * s, g00i = mq.y * c + mq.w * s;
            const float g01r = mq.z * c - mq.x * s, g01i = mq.w * c - mq.y * s;
            // lane0: new = g00*own + g01*partner ; lane1: new = conj(g00)*own - conj(g01)*partner
            const float alr = g00r;
            const float ali = h0 ? g00i : -g00i;
            const float gmr = h0 ? g01r : -g01r;
            const float gmi = g01i;
#pragma unroll
            for (int s2 = 0; s2 < 32; s2++) {
                const float orr = ar[s2], oii = ai[s2];
                const float prr = dpp1(orr);
                const float pii = dpp1(oii);
                ar[s2] = alr * orr - ali * oii + gmr * prr - gmi * pii;
                ai[s2] = alr * oii + ali * orr + gmr * pii + gmi * prr;
            }
        }
        // ---- q = 1..5: lane-local gates ----
#pragma unroll
        for (int q = 1; q < NQ; q++) {
            const float4 mq = M[layer * NQ + q];
            const float c = C[q], s = S[q];
            const float g00r = mq.x * c + mq.z * s, g00i = mq.y * c + mq.w * s;
            const float g01r = mq.z * c - mq.x * s, g01i = mq.w * c - mq.y * s;
            const int bbit = 1 << (5 - q);
#pragma unroll
            for (int s2 = 0; s2 < 32; s2++) {
                if (!(s2 & bbit)) {
                    const int t2 = s2 | bbit;
                    const float b0r = ar[s2], b0i = ai[s2];
                    const float b1r = ar[t2], b1i = ai[t2];
                    ar[s2] = g00r * b0r - g00i * b0i + g01r * b1r - g01i * b1i;
                    ai[s2] = g00r * b0i + g00i * b0r + g01r * b1i + g01i * b1r;
                    ar[t2] = -g01r * b0r - g01i * b0i + g00r * b1r + g00i * b1i;
                    ai[t2] = -g01r * b0i + g01i * b0r + g00r * b1i - g00i * b1r;
                }
            }
        }
    };

    do_ring();
    dense_layer(1);
    do_ring();
    dense_layer(2);
    do_ring();

    // ---- expvals: per-lane partials + DPP pair-reduce ----
    float P = 0.0f, T[5] = {0.f, 0.f, 0.f, 0.f, 0.f};
#pragma unroll
    for (int s2 = 0; s2 < 32; s2++) {
        const float p = ar[s2] * ar[s2] + ai[s2] * ai[s2];
        P += p;
#pragma unroll
        for (int q = 1; q < NQ; q++)
            if (s2 & (1 << (5 - q))) T[q - 1] += p;
    }
    float acc[NQ];
    {
        const float d = h0 ? P : -P;   // qubit0 sign = lane parity
        acc[0] = d + dpp1(d);
    }
    const float Ptot = P + dpp1(P);
#pragma unroll
    for (int q = 1; q < NQ; q++) {
        const float Tt = T[q - 1] + dpp1(T[q - 1]);
        acc[q] = Ptot - 2.0f * Tt;
    }
    const int off = b * 6 + (h0 ? 0 : 3);
    out[off + 0] = acc[h0 ? 0 : 3];
    out[off + 1] = acc[h0 ? 1 : 4];
    out[off + 2] = acc[h0 ? 2 : 5];
}

extern "C" void kernel_launch(void* const* d_in, const int* in_sizes, int n_in,
                              void* d_out, int out_size, void* d_ws, size_t ws_size,
                              hipStream_t stream) {
    const float* x = (const float*)d_in[0];
    const float* w = (const float*)d_in[1];
    float* out = (float*)d_out;
    float4* M = (float4*)d_ws;  // 18 * 16 B
    const int B = in_sizes[0] / NQ;
    gate_prep<<<1, 64, 0, stream>>>(w, M);
    const int threads = 2 * B;
    const int block = 256;
    const int grid = (threads + block - 1) / block;
    qsim_kernel<<<grid, block, 0, stream>>>(x, M, out, B);
}